// Round 1
// baseline (444.459 us; speedup 1.0000x reference)
//
#include <hip/hip_runtime.h>

#define N_NODES 50000
#define D_NB 16
#define IN_DIM 256
#define OUT_DIM 128
#define K_HEADS 4
#define SLOPE 0.01f

#define BM 64
#define BK 32

// ---------------- Kernel 0: transpose W (K,OUT,IN) -> Wt (K,IN,OUT) ----------------
__global__ void wt_kernel(const float* __restrict__ W, float* __restrict__ Wt) {
    int id = blockIdx.x * blockDim.x + threadIdx.x;
    if (id >= K_HEADS * IN_DIM * OUT_DIM) return;
    int o = id % OUT_DIM;
    int i = (id / OUT_DIM) % IN_DIM;
    int k = id / (OUT_DIM * IN_DIM);
    Wt[id] = W[(k * OUT_DIM + o) * IN_DIM + i];
}

// ---------------- Kernel 1: GEMM Wh[n][k][o] = sum_i X[n][i]*W[k][o][i], + e epilogue ----------------
__global__ __launch_bounds__(256) void gemm_kernel(
    const float* __restrict__ X, const float* __restrict__ Wt,
    const float* __restrict__ a,
    float* __restrict__ Wh, float* __restrict__ e_nb, float* __restrict__ e_self)
{
    __shared__ float Xs[BM][BK + 1];        // 64 x 33
    __shared__ float Ws[BK][OUT_DIM + 4];   // 32 x 132
    __shared__ float a_s[2][OUT_DIM];
    __shared__ float red[2][BM][17];

    const int k = blockIdx.y;
    const int nb = blockIdx.x * BM;
    const int t = threadIdx.x;
    const int tc = t & 15;    // 16 out-groups of 8
    const int tr = t >> 4;    // 16 node-groups of 4

    if (t < 2 * OUT_DIM) a_s[t >> 7][t & 127] = a[k * 2 * OUT_DIM + t];

    float acc[4][8] = {};

    for (int i0 = 0; i0 < IN_DIM; i0 += BK) {
        // stage X tile: 64 rows x 32 cols. thread: row r = t>>2, quarter q = t&3 -> cols q*8..q*8+7
        {
            int r = t >> 2, q = t & 3;
            int n = nb + r;
            float4 v0, v1;
            if (n < N_NODES) {
                const float4* src = (const float4*)(X + (size_t)n * IN_DIM + i0 + q * 8);
                v0 = src[0];
                v1 = src[1];
            } else {
                v0 = float4{0.f, 0.f, 0.f, 0.f};
                v1 = v0;
            }
            float* dst = &Xs[r][q * 8];
            dst[0] = v0.x; dst[1] = v0.y; dst[2] = v0.z; dst[3] = v0.w;
            dst[4] = v1.x; dst[5] = v1.y; dst[6] = v1.z; dst[7] = v1.w;
        }
        // stage W tile (already transposed): 32 rows x 128 cols. thread: i = t>>3, seg = t&7 -> cols seg*16..+15
        {
            int i = t >> 3, seg = t & 7;
            const float4* src = (const float4*)(Wt + ((size_t)k * IN_DIM + i0 + i) * OUT_DIM + seg * 16);
            float* dst = &Ws[i][seg * 16];
            #pragma unroll
            for (int f = 0; f < 4; ++f) {
                float4 v = src[f];
                dst[f * 4 + 0] = v.x; dst[f * 4 + 1] = v.y;
                dst[f * 4 + 2] = v.z; dst[f * 4 + 3] = v.w;
            }
        }
        __syncthreads();

        #pragma unroll
        for (int i = 0; i < BK; ++i) {
            float xv[4];
            #pragma unroll
            for (int j = 0; j < 4; ++j) xv[j] = Xs[tr * 4 + j][i];
            float wv[8];
            #pragma unroll
            for (int oo = 0; oo < 8; ++oo) wv[oo] = Ws[i][tc * 8 + oo];
            #pragma unroll
            for (int j = 0; j < 4; ++j)
                #pragma unroll
                for (int oo = 0; oo < 8; ++oo)
                    acc[j][oo] += xv[j] * wv[oo];
        }
        __syncthreads();
    }

    // epilogue: write Wh (layout [n][k][o]) and e partials
    float pnb[4], pself[4];
    #pragma unroll
    for (int j = 0; j < 4; ++j) {
        int n = nb + tr * 4 + j;
        float s0 = 0.f, s1 = 0.f;
        #pragma unroll
        for (int oo = 0; oo < 8; ++oo) {
            s0 += acc[j][oo] * a_s[0][tc * 8 + oo];
            s1 += acc[j][oo] * a_s[1][tc * 8 + oo];
        }
        pnb[j] = s0; pself[j] = s1;
        if (n < N_NODES) {
            float* dst = Wh + ((size_t)n * K_HEADS + k) * OUT_DIM + tc * 8;
            ((float4*)dst)[0] = float4{acc[j][0], acc[j][1], acc[j][2], acc[j][3]};
            ((float4*)dst)[1] = float4{acc[j][4], acc[j][5], acc[j][6], acc[j][7]};
        }
    }
    #pragma unroll
    for (int j = 0; j < 4; ++j) {
        red[0][tr * 4 + j][tc] = pnb[j];
        red[1][tr * 4 + j][tc] = pself[j];
    }
    __syncthreads();
    if (t < BM) {
        float s0 = 0.f, s1 = 0.f;
        #pragma unroll
        for (int c = 0; c < 16; ++c) { s0 += red[0][t][c]; s1 += red[1][t][c]; }
        int n = nb + t;
        if (n < N_NODES) {
            e_nb[(size_t)n * K_HEADS + k] = s0;
            e_self[(size_t)n * K_HEADS + k] = s1;
        }
    }
}

// ---------------- Kernel 2: gather + softmax + weighted aggregate ----------------
__global__ __launch_bounds__(256) void attn_kernel(
    const int* __restrict__ nidx, const float* __restrict__ Wh,
    const float* __restrict__ e_nb, const float* __restrict__ e_self,
    float* __restrict__ out)
{
    const int w = threadIdx.x >> 6;       // wave in block (0..3)
    const int lane = threadIdx.x & 63;
    const int item = blockIdx.x * 4 + w;  // item < N*K
    const int n = item >> 2;
    const int k = item & 3;

    float alpha = 0.f;
    int nbr = 0;
    if (lane < D_NB) {
        nbr = nidx[(size_t)n * D_NB + lane];
        float x = e_nb[(size_t)nbr * K_HEADS + k] + e_self[(size_t)n * K_HEADS + k];
        float v = x > 0.f ? x : SLOPE * x;
        float m = v;
        #pragma unroll
        for (int s = 8; s >= 1; s >>= 1) m = fmaxf(m, __shfl_xor(m, s, 16));
        float p = __expf(v - m);
        float sum = p;
        #pragma unroll
        for (int s = 8; s >= 1; s >>= 1) sum += __shfl_xor(sum, s, 16);
        alpha = p / sum;
    }

    float2 acc = {0.f, 0.f};
    #pragma unroll
    for (int d = 0; d < D_NB; ++d) {
        float ad = __shfl(alpha, d, 64);
        int nd = __shfl(nbr, d, 64);
        const float2* row = (const float2*)(Wh + ((size_t)nd * K_HEADS + k) * OUT_DIM);
        float2 v = row[lane];
        acc.x += ad * v.x;
        acc.y += ad * v.y;
    }
    ((float2*)(out + (size_t)n * (K_HEADS * OUT_DIM) + k * OUT_DIM))[lane] = acc;
}

// ---------------- launch ----------------
extern "C" void kernel_launch(void* const* d_in, const int* in_sizes, int n_in,
                              void* d_out, int out_size, void* d_ws, size_t ws_size,
                              hipStream_t stream) {
    const float* X = (const float*)d_in[0];
    const float* W = (const float*)d_in[1];
    const float* a = (const float*)d_in[2];
    const int* nidx = (const int*)d_in[3];
    float* out = (float*)d_out;

    float* Wt = (float*)d_ws;                                     // K*IN*OUT
    float* Wh = Wt + (size_t)K_HEADS * IN_DIM * OUT_DIM;          // N*K*OUT
    float* enb = Wh + (size_t)N_NODES * K_HEADS * OUT_DIM;        // N*K
    float* eself = enb + (size_t)N_NODES * K_HEADS;               // N*K

    hipLaunchKernelGGL(wt_kernel,
        dim3((K_HEADS * IN_DIM * OUT_DIM + 255) / 256), dim3(256), 0, stream, W, Wt);

    dim3 g2((N_NODES + BM - 1) / BM, K_HEADS);
    hipLaunchKernelGGL(gemm_kernel, g2, dim3(256), 0, stream, X, Wt, a, Wh, enb, eself);

    hipLaunchKernelGGL(attn_kernel,
        dim3(N_NODES * K_HEADS / 4), dim3(256), 0, stream, nidx, Wh, enb, eself, out);
}

// Round 2
// 260.260 us; speedup vs baseline: 1.7078x; 1.7078x over previous
//
#include <hip/hip_runtime.h>

#define N_NODES 50000
#define D_NB 16
#define IN_DIM 256
#define OUT_DIM 128
#define K_HEADS 4
#define SLOPE 0.01f

typedef __attribute__((ext_vector_type(8))) short short8;
typedef __attribute__((ext_vector_type(4))) float f32x4;

static __device__ __forceinline__ unsigned short f2bf(float f) {
    unsigned u = __float_as_uint(f);
    unsigned r = u + 0x7fffu + ((u >> 16) & 1u);   // RNE
    return (unsigned short)(r >> 16);
}
static __device__ __forceinline__ float bf2f(unsigned short b) {
    return __uint_as_float(((unsigned)b) << 16);
}

// ---------------- Kernel 0: convert W (f32, [K][OUT][IN]) -> Wb (bf16, same layout) ----------------
__global__ void wb_kernel(const float* __restrict__ W, unsigned short* __restrict__ Wb) {
    int id = blockIdx.x * blockDim.x + threadIdx.x;
    if (id < K_HEADS * OUT_DIM * IN_DIM) Wb[id] = f2bf(W[id]);
}

// ---------------- Kernel 1: MFMA GEMM Wh[n][k*128+o] (bf16) + e epilogue ----------------
// Block: 256 thr = 4 waves; each wave does 16 rows x 128 cols (one head = blockIdx.y).
// A-frag: direct from X (f32->bf16 in reg). B-frag: direct from Wb (16B contiguous, k-major).
__global__ __launch_bounds__(256) void gemm_kernel(
    const float* __restrict__ X, const unsigned short* __restrict__ Wb,
    const float* __restrict__ a,
    unsigned short* __restrict__ Whb, float* __restrict__ e_nb, float* __restrict__ e_self)
{
    const int k = blockIdx.y;
    const int w = threadIdx.x >> 6;
    const int lane = threadIdx.x & 63;
    const int lrow = lane & 15;   // M/N index within fragment
    const int lk = lane >> 4;     // k-chunk 0..3
    const int m0 = blockIdx.x * 64 + w * 16;

    const int arow = m0 + lrow;
    const bool avalid = arow < N_NODES;
    const float* Xrow = X + (size_t)arow * IN_DIM;

    f32x4 acc[8] = {};

    #pragma unroll
    for (int kk = 0; kk < IN_DIM / 32; ++kk) {
        const int k0 = kk * 32 + lk * 8;
        // A fragment: 8 consecutive f32 from X -> bf16
        short8 af;
        if (avalid) {
            float4 a0 = *(const float4*)(Xrow + k0);
            float4 a1 = *(const float4*)(Xrow + k0 + 4);
            af[0] = (short)f2bf(a0.x); af[1] = (short)f2bf(a0.y);
            af[2] = (short)f2bf(a0.z); af[3] = (short)f2bf(a0.w);
            af[4] = (short)f2bf(a1.x); af[5] = (short)f2bf(a1.y);
            af[6] = (short)f2bf(a1.z); af[7] = (short)f2bf(a1.w);
        } else {
            af = short8{0,0,0,0,0,0,0,0};
        }
        // B fragments: Wb[(k*128 + nt*16 + lrow)][k0 .. k0+7]  (16B contiguous)
        #pragma unroll
        for (int nt = 0; nt < 8; ++nt) {
            const short8 bf = *(const short8*)(Wb + ((size_t)(k * OUT_DIM + nt * 16 + lrow)) * IN_DIM + k0);
            acc[nt] = __builtin_amdgcn_mfma_f32_16x16x32_bf16(af, bf, acc[nt], 0, 0, 0);
        }
    }

    // preload attention vector values for this lane's columns
    float anb[8], asf[8];
    #pragma unroll
    for (int nt = 0; nt < 8; ++nt) {
        anb[nt] = a[k * 2 * OUT_DIM + nt * 16 + lrow];
        asf[nt] = a[k * 2 * OUT_DIM + OUT_DIM + nt * 16 + lrow];
    }

    // epilogue: D row = lk*4 + r, col = nt*16 + lrow
    #pragma unroll
    for (int r = 0; r < 4; ++r) {
        const int row = m0 + lk * 4 + r;
        float pnb = 0.f, psf = 0.f;
        #pragma unroll
        for (int nt = 0; nt < 8; ++nt) {
            pnb += acc[nt][r] * anb[nt];
            psf += acc[nt][r] * asf[nt];
        }
        #pragma unroll
        for (int s = 1; s < 16; s <<= 1) {
            pnb += __shfl_xor(pnb, s, 16);
            psf += __shfl_xor(psf, s, 16);
        }
        if (row < N_NODES) {
            unsigned short* dst = Whb + (size_t)row * (K_HEADS * OUT_DIM) + k * OUT_DIM;
            #pragma unroll
            for (int nt = 0; nt < 8; ++nt) dst[nt * 16 + lrow] = f2bf(acc[nt][r]);
            if (lrow == 0) {
                e_nb[(size_t)row * K_HEADS + k] = pnb;
                e_self[(size_t)row * K_HEADS + k] = psf;
            }
        }
    }
}

// ---------------- Kernel 2: gather + softmax + weighted aggregate (bf16 Wh) ----------------
__global__ __launch_bounds__(256) void attn_kernel(
    const int* __restrict__ nidx, const unsigned short* __restrict__ Whb,
    const float* __restrict__ e_nb, const float* __restrict__ e_self,
    float* __restrict__ out)
{
    const int w = threadIdx.x >> 6;
    const int lane = threadIdx.x & 63;
    const int item = blockIdx.x * 4 + w;  // item < N*K
    const int n = item >> 2;
    const int k = item & 3;

    float alpha = 0.f;
    int nbr = 0;
    if (lane < D_NB) {
        nbr = nidx[(size_t)n * D_NB + lane];
        float x = e_nb[(size_t)nbr * K_HEADS + k] + e_self[(size_t)n * K_HEADS + k];
        float v = x > 0.f ? x : SLOPE * x;
        float m = v;
        #pragma unroll
        for (int s = 8; s >= 1; s >>= 1) m = fmaxf(m, __shfl_xor(m, s, 16));
        float p = __expf(v - m);
        float sum = p;
        #pragma unroll
        for (int s = 8; s >= 1; s >>= 1) sum += __shfl_xor(sum, s, 16);
        alpha = p / sum;
    }

    float2 acc = {0.f, 0.f};
    #pragma unroll
    for (int d = 0; d < D_NB; ++d) {
        float ad = __shfl(alpha, d, 64);
        int nd = __shfl(nbr, d, 64);
        unsigned u = *(const unsigned*)(Whb + ((size_t)nd * K_HEADS + k) * OUT_DIM + lane * 2);
        acc.x += ad * bf2f((unsigned short)(u & 0xffffu));
        acc.y += ad * bf2f((unsigned short)(u >> 16));
    }
    ((float2*)(out + (size_t)n * (K_HEADS * OUT_DIM) + k * OUT_DIM))[lane] = acc;
}

// ---------------- launch ----------------
extern "C" void kernel_launch(void* const* d_in, const int* in_sizes, int n_in,
                              void* d_out, int out_size, void* d_ws, size_t ws_size,
                              hipStream_t stream) {
    const float* X = (const float*)d_in[0];
    const float* W = (const float*)d_in[1];
    const float* a = (const float*)d_in[2];
    const int* nidx = (const int*)d_in[3];
    float* out = (float*)d_out;

    char* p = (char*)d_ws;
    unsigned short* Wb = (unsigned short*)p;                 p += (size_t)K_HEADS * OUT_DIM * IN_DIM * 2;
    unsigned short* Whb = (unsigned short*)p;                p += (size_t)N_NODES * K_HEADS * OUT_DIM * 2;
    float* enb = (float*)p;                                  p += (size_t)N_NODES * K_HEADS * 4;
    float* eself = (float*)p;

    hipLaunchKernelGGL(wb_kernel,
        dim3((K_HEADS * OUT_DIM * IN_DIM + 255) / 256), dim3(256), 0, stream, W, Wb);

    dim3 g2((N_NODES + 63) / 64, K_HEADS);
    hipLaunchKernelGGL(gemm_kernel, g2, dim3(256), 0, stream, X, Wb, a, Whb, enb, eself);

    hipLaunchKernelGGL(attn_kernel,
        dim3(N_NODES * K_HEADS / 4), dim3(256), 0, stream, nidx, Whb, enb, eself, out);
}

// Round 3
// 220.518 us; speedup vs baseline: 2.0155x; 1.1802x over previous
//
#include <hip/hip_runtime.h>

#define N_NODES 50000
#define D_NB 16
#define IN_DIM 256
#define OUT_DIM 128
#define K_HEADS 4
#define SLOPE 0.01f

typedef __attribute__((ext_vector_type(8))) short short8;
typedef __attribute__((ext_vector_type(4))) float f32x4;

static __device__ __forceinline__ unsigned short f2bf(float f) {
    unsigned u = __float_as_uint(f);
    unsigned r = u + 0x7fffu + ((u >> 16) & 1u);   // RNE
    return (unsigned short)(r >> 16);
}
static __device__ __forceinline__ float bf2f(unsigned short b) {
    return __uint_as_float(((unsigned)b) << 16);
}

// ---------------- Kernel 0: W (f32) -> Wb (bf16), same [K][OUT][IN] layout ----------------
__global__ void wb_kernel(const float* __restrict__ W, unsigned short* __restrict__ Wb) {
    int id = blockIdx.x * blockDim.x + threadIdx.x;
    if (id < K_HEADS * OUT_DIM * IN_DIM) Wb[id] = f2bf(W[id]);
}

// ---------------- Kernel 1: MFMA GEMM, 128 rows/block, all 4 heads internal ----------------
// 4 waves; wave w owns rows m0=bx*128+w*32 (2 M-frags). A (X rows) kept in registers for all
// K; per head, W staged to LDS (XOR-swizzled 16B chunks), B-frags via ds_read_b128.
// MFMA operand-swapped: acc = mfma(W_frag, X_frag) -> lane holds 4 consecutive out-cols.
__global__ __launch_bounds__(256) void gemm_kernel(
    const float* __restrict__ X, const unsigned short* __restrict__ Wb,
    const float* __restrict__ a,
    unsigned short* __restrict__ Whb, float* __restrict__ e_nb, float* __restrict__ e_self)
{
    __shared__ unsigned short Wlds[OUT_DIM * IN_DIM];   // 64 KB

    const int t = threadIdx.x;
    const int lane = t & 63;
    const int w = t >> 6;
    const int lrow = lane & 15;
    const int lk = lane >> 4;
    const int m0 = blockIdx.x * 128 + w * 32;

    // ---- A fragments: af[mf][kk], resident for whole kernel ----
    short8 af[2][8];
    #pragma unroll
    for (int mf = 0; mf < 2; ++mf) {
        const int row = m0 + mf * 16 + lrow;
        const bool valid = row < N_NODES;
        const float* Xr = X + (size_t)row * IN_DIM + lk * 8;
        #pragma unroll
        for (int kk = 0; kk < 8; ++kk) {
            short8 s;
            if (valid) {
                float4 x0 = *(const float4*)(Xr + kk * 32);
                float4 x1 = *(const float4*)(Xr + kk * 32 + 4);
                s[0] = (short)f2bf(x0.x); s[1] = (short)f2bf(x0.y);
                s[2] = (short)f2bf(x0.z); s[3] = (short)f2bf(x0.w);
                s[4] = (short)f2bf(x1.x); s[5] = (short)f2bf(x1.y);
                s[6] = (short)f2bf(x1.z); s[7] = (short)f2bf(x1.w);
            } else {
                s = short8{0, 0, 0, 0, 0, 0, 0, 0};
            }
            af[mf][kk] = s;
        }
    }

    for (int k = 0; k < K_HEADS; ++k) {
        if (k) __syncthreads();   // previous head's LDS reads done
        // ---- stage W head into LDS, XOR-swizzled: pos = chunk ^ (row&7) ----
        {
            const unsigned short* Wh0 = Wb + (size_t)k * OUT_DIM * IN_DIM;
            #pragma unroll
            for (int i = 0; i < 16; ++i) {
                const int c = i * 256 + t;       // linear 16B-chunk id
                const int r = c >> 5;            // out-row
                const int p = c & 31;            // swizzled chunk pos in row
                const int cu = p ^ (r & 7);      // original chunk
                *(short8*)(&Wlds[c * 8]) = *(const short8*)(Wh0 + r * IN_DIM + cu * 8);
            }
        }
        __syncthreads();

        f32x4 acc[2][8] = {};
        #pragma unroll
        for (int kk = 0; kk < 8; ++kk) {
            const int pos = (kk * 4 + lk) ^ (lrow & 7);
            #pragma unroll
            for (int nt = 0; nt < 8; ++nt) {
                const short8 bf = *(const short8*)(&Wlds[(nt * 16 + lrow) * IN_DIM + pos * 8]);
                acc[0][nt] = __builtin_amdgcn_mfma_f32_16x16x32_bf16(bf, af[0][kk], acc[0][nt], 0, 0, 0);
                acc[1][nt] = __builtin_amdgcn_mfma_f32_16x16x32_bf16(bf, af[1][kk], acc[1][nt], 0, 0, 0);
            }
        }

        // ---- epilogue: lane holds out-cols nt*16 + lk*4 + r for X-row m0 + mf*16 + lrow ----
        float4 anb[8], asf[8];
        #pragma unroll
        for (int nt = 0; nt < 8; ++nt) {
            anb[nt] = *(const float4*)(a + k * 2 * OUT_DIM + nt * 16 + lk * 4);
            asf[nt] = *(const float4*)(a + k * 2 * OUT_DIM + OUT_DIM + nt * 16 + lk * 4);
        }
        #pragma unroll
        for (int mf = 0; mf < 2; ++mf) {
            const int row = m0 + mf * 16 + lrow;
            float pnb = 0.f, psf = 0.f;
            #pragma unroll
            for (int nt = 0; nt < 8; ++nt) {
                pnb += acc[mf][nt][0] * anb[nt].x + acc[mf][nt][1] * anb[nt].y
                     + acc[mf][nt][2] * anb[nt].z + acc[mf][nt][3] * anb[nt].w;
                psf += acc[mf][nt][0] * asf[nt].x + acc[mf][nt][1] * asf[nt].y
                     + acc[mf][nt][2] * asf[nt].z + acc[mf][nt][3] * asf[nt].w;
            }
            pnb += __shfl_xor(pnb, 16); pnb += __shfl_xor(pnb, 32);
            psf += __shfl_xor(psf, 16); psf += __shfl_xor(psf, 32);
            if (row < N_NODES) {
                unsigned short* dst = Whb + (size_t)row * (K_HEADS * OUT_DIM) + k * OUT_DIM;
                #pragma unroll
                for (int nt = 0; nt < 8; ++nt) {
                    uint2 pk;
                    pk.x = (unsigned)f2bf(acc[mf][nt][0]) | ((unsigned)f2bf(acc[mf][nt][1]) << 16);
                    pk.y = (unsigned)f2bf(acc[mf][nt][2]) | ((unsigned)f2bf(acc[mf][nt][3]) << 16);
                    *(uint2*)(dst + nt * 16 + lk * 4) = pk;
                }
                if (lk == 0) {
                    e_nb[(size_t)row * K_HEADS + k] = pnb;
                    e_self[(size_t)row * K_HEADS + k] = psf;
                }
            }
        }
    }
}

// ---------------- Kernel 2: gather + softmax + aggregate; 1 wave = 1 node, all 4 heads ----------------
__global__ __launch_bounds__(256) void attn_kernel(
    const int* __restrict__ nidx, const unsigned short* __restrict__ Whb,
    const float* __restrict__ e_nb, const float* __restrict__ e_self,
    float* __restrict__ out)
{
    const int w = threadIdx.x >> 6;
    const int lane = threadIdx.x & 63;
    const int n = blockIdx.x * 4 + w;
    const int kl = lane >> 4;   // head for this lane
    const int dl = lane & 15;   // neighbor slot

    const int nbr = nidx[(size_t)n * D_NB + dl];
    const float x = e_nb[(size_t)nbr * K_HEADS + kl] + e_self[(size_t)n * K_HEADS + kl];
    const float v = x > 0.f ? x : SLOPE * x;
    float m = v;
    #pragma unroll
    for (int s = 8; s >= 1; s >>= 1) m = fmaxf(m, __shfl_xor(m, s, 16));
    const float p = __expf(v - m);
    float sum = p;
    #pragma unroll
    for (int s = 8; s >= 1; s >>= 1) sum += __shfl_xor(sum, s, 16);
    const float alpha = p / sum;

    float acc[8] = {};
    #pragma unroll
    for (int d = 0; d < D_NB; ++d) {
        const float ad = __shfl(alpha, kl * 16 + d);
        const int nd = __shfl(nbr, d);
        const short8 v8 = *(const short8*)(Whb + (size_t)nd * (K_HEADS * OUT_DIM) + lane * 8);
        #pragma unroll
        for (int j = 0; j < 8; ++j) acc[j] += ad * bf2f((unsigned short)v8[j]);
    }
    float* op = out + (size_t)n * (K_HEADS * OUT_DIM) + lane * 8;
    *(float4*)op       = float4{acc[0], acc[1], acc[2], acc[3]};
    *(float4*)(op + 4) = float4{acc[4], acc[5], acc[6], acc[7]};
}

// ---------------- launch ----------------
extern "C" void kernel_launch(void* const* d_in, const int* in_sizes, int n_in,
                              void* d_out, int out_size, void* d_ws, size_t ws_size,
                              hipStream_t stream) {
    const float* X = (const float*)d_in[0];
    const float* W = (const float*)d_in[1];
    const float* a = (const float*)d_in[2];
    const int* nidx = (const int*)d_in[3];
    float* out = (float*)d_out;

    char* p = (char*)d_ws;
    unsigned short* Wb = (unsigned short*)p;      p += (size_t)K_HEADS * OUT_DIM * IN_DIM * 2;
    unsigned short* Whb = (unsigned short*)p;     p += (size_t)N_NODES * K_HEADS * OUT_DIM * 2;
    float* enb = (float*)p;                       p += (size_t)N_NODES * K_HEADS * 4;
    float* eself = (float*)p;

    hipLaunchKernelGGL(wb_kernel,
        dim3((K_HEADS * OUT_DIM * IN_DIM + 255) / 256), dim3(256), 0, stream, W, Wb);

    hipLaunchKernelGGL(gemm_kernel,
        dim3((N_NODES + 127) / 128), dim3(256), 0, stream, X, Wb, a, Whb, enb, eself);

    hipLaunchKernelGGL(attn_kernel,
        dim3(N_NODES / 4), dim3(256), 0, stream, nidx, Whb, enb, eself, out);
}

// Round 5
// 185.252 us; speedup vs baseline: 2.3992x; 1.1904x over previous
//
#include <hip/hip_runtime.h>

#define N_NODES 50000
#define D_NB 16
#define IN_DIM 256
#define OUT_DIM 128
#define K_HEADS 4
#define SLOPE 0.01f

typedef __attribute__((ext_vector_type(8))) short short8;
typedef __attribute__((ext_vector_type(4))) float f32x4;

static __device__ __forceinline__ unsigned short f2bf(float f) {
    unsigned u = __float_as_uint(f);
    unsigned r = u + 0x7fffu + ((u >> 16) & 1u);   // RNE
    return (unsigned short)(r >> 16);
}
static __device__ __forceinline__ float bf2f(unsigned short b) {
    return __uint_as_float(((unsigned)b) << 16);
}

// ---------------- Kernel 0: W (f32) -> Wb (bf16), same [K][OUT][IN] layout ----------------
__global__ void wb_kernel(const float* __restrict__ W, unsigned short* __restrict__ Wb) {
    int id = blockIdx.x * blockDim.x + threadIdx.x;
    if (id < K_HEADS * OUT_DIM * IN_DIM) Wb[id] = f2bf(W[id]);
}

// ---------------- Kernel 1: MFMA GEMM, 64 rows/block, 4 heads x 2 half-W stages ----------------
// 4 waves; wave w owns rows m0 = bx*64 + w*16 (1 M-frag, X in regs for all K).
// Per (head, half): 64 out-cols x 256 in staged to 32KB LDS via global_load_lds
// (pre-swizzled global source, linear LDS dest); consumed swizzled via ds_read_b128.
// MFMA operand-swapped: acc = mfma(W_frag, X_frag) -> lane holds 4 consecutive out-cols.
__global__ __launch_bounds__(256) void gemm_kernel(
    const float* __restrict__ X, const unsigned short* __restrict__ Wb,
    const float* __restrict__ a,
    unsigned short* __restrict__ Whb, float* __restrict__ e_nb, float* __restrict__ e_self)
{
    __shared__ unsigned short Wlds[64 * IN_DIM];   // 32 KB

    const int t = threadIdx.x;
    const int lane = t & 63;
    const int w = t >> 6;
    const int lrow = lane & 15;
    const int lk = lane >> 4;
    const int m0 = blockIdx.x * 64 + w * 16;

    // ---- A fragments: af[kk], resident for whole kernel ----
    const int arow = m0 + lrow;
    const bool avalid = arow < N_NODES;
    const float* Xr = X + (size_t)arow * IN_DIM + lk * 8;
    short8 af[8];
    #pragma unroll
    for (int kk = 0; kk < 8; ++kk) {
        short8 s;
        if (avalid) {
            float4 x0 = *(const float4*)(Xr + kk * 32);
            float4 x1 = *(const float4*)(Xr + kk * 32 + 4);
            s[0] = (short)f2bf(x0.x); s[1] = (short)f2bf(x0.y);
            s[2] = (short)f2bf(x0.z); s[3] = (short)f2bf(x0.w);
            s[4] = (short)f2bf(x1.x); s[5] = (short)f2bf(x1.y);
            s[6] = (short)f2bf(x1.z); s[7] = (short)f2bf(x1.w);
        } else {
            s = short8{0, 0, 0, 0, 0, 0, 0, 0};
        }
        af[kk] = s;
    }

    for (int k = 0; k < K_HEADS; ++k) {
        float pnb = 0.f, psf = 0.f;
        #pragma unroll
        for (int h = 0; h < 2; ++h) {
            if (k | h) __syncthreads();   // previous phase's LDS reads done
            // ---- stage 64 out-cols x 256 in: 2048 16B-chunks, swizzled source, linear dest ----
            {
                const unsigned short* WbH = Wb + ((size_t)k * OUT_DIM + h * 64) * IN_DIM;
                #pragma unroll
                for (int i = 0; i < 8; ++i) {
                    const int c = i * 256 + w * 64 + lane;  // linear chunk id
                    const int r = c >> 5;                   // out-col row (32 chunks/row)
                    const int p = c & 31;                   // LDS chunk pos (linear)
                    const int cu = p ^ (r & 7);             // source chunk (pre-swizzle)
                    const unsigned short* gsrc = WbH + r * IN_DIM + cu * 8;
                    unsigned short* ldst = &Wlds[(size_t)(i * 256 + w * 64) * 8];
                    __builtin_amdgcn_global_load_lds(
                        (const __attribute__((address_space(1))) void*)gsrc,
                        (__attribute__((address_space(3))) void*)ldst, 16, 0, 0);
                }
            }
            __syncthreads();

            f32x4 acc[4] = {};
            #pragma unroll
            for (int kk = 0; kk < 8; ++kk) {
                #pragma unroll
                for (int nt = 0; nt < 4; ++nt) {
                    const int row = nt * 16 + lrow;
                    const int pos = (kk * 4 + lk) ^ (row & 7);
                    const short8 bf = *(const short8*)(&Wlds[row * IN_DIM + pos * 8]);
                    acc[nt] = __builtin_amdgcn_mfma_f32_16x16x32_bf16(bf, af[kk], acc[nt], 0, 0, 0);
                }
            }

            // ---- epilogue: lane holds out-cols h*64 + nt*16 + lk*4 + r for X-row arow ----
            #pragma unroll
            for (int nt = 0; nt < 4; ++nt) {
                const float4 anb = *(const float4*)(a + k * 2 * OUT_DIM + h * 64 + nt * 16 + lk * 4);
                const float4 asf = *(const float4*)(a + k * 2 * OUT_DIM + OUT_DIM + h * 64 + nt * 16 + lk * 4);
                pnb += acc[nt][0] * anb.x + acc[nt][1] * anb.y
                     + acc[nt][2] * anb.z + acc[nt][3] * anb.w;
                psf += acc[nt][0] * asf.x + acc[nt][1] * asf.y
                     + acc[nt][2] * asf.z + acc[nt][3] * asf.w;
            }
            if (avalid) {
                unsigned short* dst = Whb + (size_t)arow * (K_HEADS * OUT_DIM) + k * OUT_DIM + h * 64;
                #pragma unroll
                for (int nt = 0; nt < 4; ++nt) {
                    uint2 pk;
                    pk.x = (unsigned)f2bf(acc[nt][0]) | ((unsigned)f2bf(acc[nt][1]) << 16);
                    pk.y = (unsigned)f2bf(acc[nt][2]) | ((unsigned)f2bf(acc[nt][3]) << 16);
                    *(uint2*)(dst + nt * 16 + lk * 4) = pk;
                }
            }
        }
        // ---- head done: reduce e partials across lk groups ----
        pnb += __shfl_xor(pnb, 16); pnb += __shfl_xor(pnb, 32);
        psf += __shfl_xor(psf, 16); psf += __shfl_xor(psf, 32);
        if (avalid && lane < 16) {
            e_nb[(size_t)arow * K_HEADS + k] = pnb;
            e_self[(size_t)arow * K_HEADS + k] = psf;
        }
    }
}

// ---------------- Kernel 2: gather + softmax + aggregate; 1 wave = 2 nodes, all 4 heads ----------------
__global__ __launch_bounds__(256) void attn_kernel(
    const int* __restrict__ nidx, const unsigned short* __restrict__ Whb,
    const float* __restrict__ e_nb, const float* __restrict__ e_self,
    float* __restrict__ out)
{
    const int w = threadIdx.x >> 6;
    const int lane = threadIdx.x & 63;
    const int n0 = (blockIdx.x * 4 + w) * 2;
    const int n1 = n0 + 1;
    const int kl = lane >> 4;   // head for this lane
    const int dl = lane & 15;   // neighbor slot

    const int nbr0 = nidx[(size_t)n0 * D_NB + dl];
    const int nbr1 = nidx[(size_t)n1 * D_NB + dl];
    const float x0 = e_nb[(size_t)nbr0 * K_HEADS + kl] + e_self[(size_t)n0 * K_HEADS + kl];
    const float x1 = e_nb[(size_t)nbr1 * K_HEADS + kl] + e_self[(size_t)n1 * K_HEADS + kl];
    const float v0 = x0 > 0.f ? x0 : SLOPE * x0;
    const float v1 = x1 > 0.f ? x1 : SLOPE * x1;
    float m0 = v0, m1 = v1;
    #pragma unroll
    for (int s = 8; s >= 1; s >>= 1) {
        m0 = fmaxf(m0, __shfl_xor(m0, s, 16));
        m1 = fmaxf(m1, __shfl_xor(m1, s, 16));
    }
    const float p0 = __expf(v0 - m0);
    const float p1 = __expf(v1 - m1);
    float s0 = p0, s1 = p1;
    #pragma unroll
    for (int s = 8; s >= 1; s >>= 1) {
        s0 += __shfl_xor(s0, s, 16);
        s1 += __shfl_xor(s1, s, 16);
    }
    const float alpha0 = p0 / s0;
    const float alpha1 = p1 / s1;

    float acc0[8] = {}, acc1[8] = {};
    #pragma unroll
    for (int d = 0; d < D_NB; ++d) {
        const float ad0 = __shfl(alpha0, kl * 16 + d);
        const int nd0 = __shfl(nbr0, d);
        const float ad1 = __shfl(alpha1, kl * 16 + d);
        const int nd1 = __shfl(nbr1, d);
        const short8 va = *(const short8*)(Whb + (size_t)nd0 * (K_HEADS * OUT_DIM) + lane * 8);
        const short8 vb = *(const short8*)(Whb + (size_t)nd1 * (K_HEADS * OUT_DIM) + lane * 8);
        #pragma unroll
        for (int j = 0; j < 8; ++j) {
            acc0[j] += ad0 * bf2f((unsigned short)va[j]);
            acc1[j] += ad1 * bf2f((unsigned short)vb[j]);
        }
    }
    float* op0 = out + (size_t)n0 * (K_HEADS * OUT_DIM) + lane * 8;
    *(float4*)op0       = float4{acc0[0], acc0[1], acc0[2], acc0[3]};
    *(float4*)(op0 + 4) = float4{acc0[4], acc0[5], acc0[6], acc0[7]};
    float* op1 = out + (size_t)n1 * (K_HEADS * OUT_DIM) + lane * 8;
    *(float4*)op1       = float4{acc1[0], acc1[1], acc1[2], acc1[3]};
    *(float4*)(op1 + 4) = float4{acc1[4], acc1[5], acc1[6], acc1[7]};
}

// ---------------- launch ----------------
extern "C" void kernel_launch(void* const* d_in, const int* in_sizes, int n_in,
                              void* d_out, int out_size, void* d_ws, size_t ws_size,
                              hipStream_t stream) {
    const float* X = (const float*)d_in[0];
    const float* W = (const float*)d_in[1];
    const float* a = (const float*)d_in[2];
    const int* nidx = (const int*)d_in[3];
    float* out = (float*)d_out;

    char* p = (char*)d_ws;
    unsigned short* Wb = (unsigned short*)p;      p += (size_t)K_HEADS * OUT_DIM * IN_DIM * 2;
    unsigned short* Whb = (unsigned short*)p;     p += (size_t)N_NODES * K_HEADS * OUT_DIM * 2;
    float* enb = (float*)p;                       p += (size_t)N_NODES * K_HEADS * 4;
    float* eself = (float*)p;

    hipLaunchKernelGGL(wb_kernel,
        dim3((K_HEADS * OUT_DIM * IN_DIM + 255) / 256), dim3(256), 0, stream, W, Wb);

    hipLaunchKernelGGL(gemm_kernel,
        dim3((N_NODES + 63) / 64), dim3(256), 0, stream, X, Wb, a, Whb, enb, eself);

    hipLaunchKernelGGL(attn_kernel,
        dim3(N_NODES / 8), dim3(256), 0, stream, nidx, Whb, enb, eself, out);
}